// Round 4
// baseline (111488.184 us; speedup 1.0000x reference)
//
#include <hip/hip_runtime.h>
#include <math.h>

#define NS 1024
#define SENT (-1.0e300)

template <typename T> struct V2;
template <> struct V2<double> { using t = double2; };
template <> struct V2<float>  { using t = float2; };

template <typename T> __device__ __forceinline__ T sentv();
template <> __device__ __forceinline__ double sentv<double>() { return -1.0e300; }
template <> __device__ __forceinline__ float  sentv<float>()  { return -3.0e38f; }

template <typename T>
__device__ __forceinline__ T aldT(const T* p) {
  return __hip_atomic_load(p, __ATOMIC_RELAXED, __HIP_MEMORY_SCOPE_AGENT);
}
__device__ __forceinline__ double ald(const double* p) {
  return __hip_atomic_load(p, __ATOMIC_RELAXED, __HIP_MEMORY_SCOPE_AGENT);
}
template <typename T>
__device__ __forceinline__ void ast(T* p, T v) {
  __hip_atomic_store(p, v, __ATOMIC_RELAXED, __HIP_MEMORY_SCOPE_AGENT);
}

// ---------------------------------------------------------------- init (legacy)
template <typename TR>
__global__ void k_init(double* __restrict__ wbuf, TR* __restrict__ Rbuf) {
  size_t stride = (size_t)gridDim.x * blockDim.x;
  size_t t = (size_t)blockIdx.x * blockDim.x + threadIdx.x;
  for (size_t idx = t; idx < (size_t)(NS + 1) * 128; idx += stride)
    wbuf[idx] = (idx < 128) ? ((idx == 0) ? 1.0 : 0.0) : SENT;
  const size_t lastoff = (size_t)(NS - 1) * 16384;
  for (size_t idx = t; idx < (size_t)NS * 16384; idx += stride)
    Rbuf[idx] = (idx < lastoff) ? sentv<TR>()
                                : (TR)((idx == lastoff) ? 1.0f : 0.0f);
}

// ---------------------------------------------------------------- init (pair plan)
__global__ void k_init2(double* __restrict__ wbuf, double* __restrict__ Rodd) {
  size_t stride = (size_t)gridDim.x * blockDim.x;
  size_t t = (size_t)blockIdx.x * blockDim.x + threadIdx.x;
  for (size_t idx = t; idx < (size_t)513 * 128; idx += stride)
    wbuf[idx] = (idx < 128) ? ((idx == 0) ? 1.0 : 0.0) : SENT;
  const size_t lastoff = (size_t)511 * 16384;
  for (size_t idx = t; idx < (size_t)512 * 16384; idx += stride)
    Rodd[idx] = (idx < lastoff) ? SENT : ((idx == lastoff) ? 1.0 : 0.0);
}

// ---------------------------------------------------------------- cayley
template <typename TT, typename TR>
__global__ __launch_bounds__(256) void k_cayley(const float* __restrict__ params,
                                                TT* __restrict__ Tk,
                                                TR* __restrict__ Yscr) {
  __shared__ float XB[64 * 132];
  __shared__ double prow[128], fcol[128];
  const int site = blockIdx.x, tid = threadIdx.x;
  const float* X = params + (size_t)site * 256 * 128;
  const int ti = tid >> 4, tj = tid & 15;
  const int R0 = ti * 8, C0 = tj * 8;
  double g[8][8];
  #pragma unroll
  for (int i = 0; i < 8; ++i)
    #pragma unroll
    for (int j = 0; j < 8; ++j) g[i][j] = ((R0 + i) == (C0 + j)) ? 1.0 : 0.0;
  for (int h = 0; h < 2; ++h) {
    for (int idx = tid; idx < 64 * 128; idx += 256) {
      int rr = idx >> 7, c = idx & 127;
      XB[rr * 132 + c] = X[(size_t)(h * 64 + rr) * 128 + c];
    }
    __syncthreads();
    int lo = h * 64;
    if ((R0 >> 6) == h) {
      #pragma unroll
      for (int i = 0; i < 8; ++i)
        #pragma unroll
        for (int j = 0; j < 8; ++j)
          g[i][j] += 0.5 * (double)XB[(R0 + i - lo) * 132 + (C0 + j)];
    }
    if ((C0 >> 6) == h) {
      #pragma unroll
      for (int i = 0; i < 8; ++i)
        #pragma unroll
        for (int j = 0; j < 8; ++j)
          g[i][j] -= 0.5 * (double)XB[(C0 + j - lo) * 132 + (R0 + i)];
    }
    __syncthreads();
  }
  for (int h = 0; h < 2; ++h) {
    for (int idx = tid; idx < 64 * 128; idx += 256) {
      int rr = idx >> 7, c = idx & 127;
      XB[rr * 132 + c] = X[(size_t)(128 + h * 64 + rr) * 128 + c];
    }
    __syncthreads();
    for (int a = 0; a < 64; ++a) {
      double fa[8], fb[8];
      #pragma unroll
      for (int i = 0; i < 8; ++i) fa[i] = 0.5 * (double)XB[a * 132 + R0 + i];
      #pragma unroll
      for (int j = 0; j < 8; ++j) fb[j] = 0.5 * (double)XB[a * 132 + C0 + j];
      #pragma unroll
      for (int i = 0; i < 8; ++i)
        #pragma unroll
        for (int j = 0; j < 8; ++j) g[i][j] += fa[i] * fb[j];
    }
    __syncthreads();
  }
  for (int p = 0; p < 128; ++p) {
    int pb = p >> 3, pl = p & 7;
    if (ti == pb) {
      #pragma unroll
      for (int j = 0; j < 8; ++j) prow[C0 + j] = g[pl][j];
    }
    if (tj == pb) {
      #pragma unroll
      for (int i = 0; i < 8; ++i) fcol[R0 + i] = g[i][pl];
    }
    __syncthreads();
    double d = 1.0 / prow[p];
    double pd[8];
    #pragma unroll
    for (int j = 0; j < 8; ++j) pd[j] = prow[C0 + j] * d;
    #pragma unroll
    for (int i = 0; i < 8; ++i) {
      int r = R0 + i;
      if (r == p) {
        #pragma unroll
        for (int j = 0; j < 8; ++j) g[i][j] = ((C0 + j) == p) ? d : pd[j];
      } else {
        double f = fcol[r];
        #pragma unroll
        for (int j = 0; j < 8; ++j)
          g[i][j] = ((C0 + j) == p) ? (-f * d) : (g[i][j] - f * pd[j]);
      }
    }
    __syncthreads();
  }
  TR* Ys = Yscr + (size_t)site * 16384;
  TT* Ts = Tk + (size_t)site * 32768;
  #pragma unroll
  for (int i = 0; i < 8; ++i) {
    int r = R0 + i, s = r & 1, a = r >> 1;
    #pragma unroll
    for (int j = 0; j < 8; ++j) {
      int c = C0 + j;
      Ys[(size_t)r * 128 + c] = (TR)g[i][j];
      Ts[((size_t)s * 128 + a) * 128 + c] =
          (TT)(2.0 * g[i][j] - ((r == c) ? 1.0 : 0.0));
    }
  }
}

// ---------------------------------------------------------------- W_bot = -X2 * Y
template <typename TT, typename TR>
__global__ __launch_bounds__(256) void k_w2(const float* __restrict__ params,
                                            const TR* __restrict__ Yscr,
                                            TT* __restrict__ Tk) {
  __shared__ float X2c[16 * 132];
  __shared__ double Yt[16 * 130];
  const int site = blockIdx.x, tid = threadIdx.x;
  const float* X2g = params + (size_t)site * 256 * 128 + 128 * 128;
  const TR* Ys = Yscr + (size_t)site * 16384;
  TT* Ts = Tk + (size_t)site * 32768;
  const int ti = tid >> 4, tj = tid & 15;
  const int R0 = ti * 8, C0 = tj * 8;
  double acc[8][8];
  #pragma unroll
  for (int i = 0; i < 8; ++i)
    #pragma unroll
    for (int j = 0; j < 8; ++j) acc[i][j] = 0.0;
  for (int b0 = 0; b0 < 128; b0 += 16) {
    __syncthreads();
    for (int idx = tid; idx < 2048; idx += 256) {
      int r = idx >> 4, bb = idx & 15;
      X2c[bb * 132 + r] = X2g[(size_t)r * 128 + b0 + bb];
    }
    for (int idx = tid; idx < 2048; idx += 256) {
      int bb = idx >> 7, c = idx & 127;
      Yt[bb * 130 + c] = (double)Ys[(size_t)(b0 + bb) * 128 + c];
    }
    __syncthreads();
    for (int bb = 0; bb < 16; ++bb) {
      double xf[8], yf[8];
      #pragma unroll
      for (int i = 0; i < 8; ++i) xf[i] = (double)X2c[bb * 132 + R0 + i];
      #pragma unroll
      for (int j = 0; j < 8; ++j) yf[j] = Yt[bb * 130 + C0 + j];
      #pragma unroll
      for (int i = 0; i < 8; ++i)
        #pragma unroll
        for (int j = 0; j < 8; ++j) acc[i][j] += xf[i] * yf[j];
    }
  }
  #pragma unroll
  for (int i = 0; i < 8; ++i) {
    int r = 128 + R0 + i, s = r & 1, a = r >> 1;
    #pragma unroll
    for (int j = 0; j < 8; ++j)
      Ts[((size_t)s * 128 + a) * 128 + C0 + j] = (TT)(-acc[i][j]);
  }
}

// ---------------------------------------------------------------- pair Kraus ops
template <typename TT>
__global__ __launch_bounds__(256) void k_pair2(const TT* __restrict__ Tk,
                                               double* __restrict__ outB,
                                               int pair0) {
  __shared__ double As[16 * 136];
  __shared__ double Bs[16 * 132];
  const int blk = blockIdx.x, tid = threadIdx.x;
  const int pl = blk >> 2, q = blk & 3, s = q >> 1, sp = q & 1;
  const int p = pair0 + pl;
  const TT* A = Tk + ((size_t)(2 * p) * 2 + s) * 16384;
  const TT* B = Tk + ((size_t)(2 * p + 1) * 2 + sp) * 16384;
  double* outp = outB + (size_t)pl * 65536 + (size_t)q * 16384;
  const int ti = tid >> 4, tj = tid & 15, R0 = ti * 8, C0 = tj * 8;
  double acc[8][8];
  #pragma unroll
  for (int i = 0; i < 8; ++i)
    #pragma unroll
    for (int j = 0; j < 8; ++j) acc[i][j] = 0.0;
  for (int b0 = 0; b0 < 128; b0 += 16) {
    __syncthreads();
    for (int idx = tid; idx < 2048; idx += 256) {
      int r = idx >> 4, bb = idx & 15;
      As[bb * 136 + r] = (double)A[(size_t)r * 128 + b0 + bb];
    }
    for (int idx = tid; idx < 2048; idx += 256) {
      int bb = idx >> 7, c = idx & 127;
      Bs[bb * 132 + c] = (double)B[(size_t)(b0 + bb) * 128 + c];
    }
    __syncthreads();
    for (int bb = 0; bb < 16; ++bb) {
      double fa[8], fb[8];
      #pragma unroll
      for (int i = 0; i < 8; ++i) fa[i] = As[bb * 136 + R0 + i];
      #pragma unroll
      for (int j = 0; j < 8; ++j) fb[j] = Bs[bb * 132 + C0 + j];
      #pragma unroll
      for (int i = 0; i < 8; ++i)
        #pragma unroll
        for (int j = 0; j < 8; ++j) acc[i][j] += fa[i] * fb[j];
    }
  }
  #pragma unroll
  for (int i = 0; i < 8; ++i)
    #pragma unroll
    for (int j = 0; j < 8; ++j)
      outp[(size_t)(R0 + i) * 128 + C0 + j] = acc[i][j];
}

// ---------------------------------------------------------------- pair-composed scan
// 512 steps, R' = sum_{j<4} B_j R B_j^T. 256 WGs x 512 thr, 4x16 tile/WG.
// Depth-1 streaming in v[8] ONLY (round-3's v[32] hit the 128-VGPR cap and
// spilled -> 194 GB scratch writes). 32-row chunks, double-buffered Rt with
// Pb aliasing buffer 0 (all compute done before Pb write): 8 barriers/step.
// Validate-AFTER-compute ordering hides the producer wait under FMAs.
__global__ __launch_bounds__(512, 2) void k_scan3(const double* __restrict__ Blo,
                                                  const double* __restrict__ Bhi,
                                                  int splitP,
                                                  double* __restrict__ Rodd,
                                                  double* __restrict__ Rs0,
                                                  double* __restrict__ Zp) {
  __shared__ double KA[16 * 128];    // 16 KB  a-rows (j,aa): row = j*4+aa
  __shared__ double KC[64 * 129];    // 66 KB  c-rows (j,cc): row = j*16+cc
  __shared__ double RtPb[2 * 4096];  // 64 KB  chunk dbuf; Pb aliases [0,2064)
  __shared__ double red[512];        // 4 KB
  double* Pb = RtPb;
  const int w = blockIdx.x, tid = threadIdx.x;
  const int a0 = (w >> 3) * 4, c0 = (w & 7) * 16;
  const int r2 = tid >> 7, bh = tid & 127;
  const int seg = tid >> 6, oi = tid & 63;
  for (int p = 511; p >= 0; --p) {
    const double* op = (p < splitP) ? (Blo + (size_t)p * 65536)
                                    : (Bhi + (size_t)(p - splitP) * 65536);
    const double* Rin = Rodd + (size_t)p * 16384;
    // issue chunk-0 loads first (latency-critical), then stage KA/KC under them
    double v[8];
    #pragma unroll
    for (int u = 0; u < 8; ++u) v[u] = ald(Rin + u * 512 + tid);
    for (int idx = tid; idx < 2048; idx += 512) {
      int row = idx >> 7, col = idx & 127;
      KA[idx] =
          op[(size_t)(row >> 2) * 16384 + (size_t)(a0 + (row & 3)) * 128 + col];
    }
    #pragma unroll
    for (int u = 0; u < 16; ++u) {
      int row = r2 + 4 * u;
      KC[row * 129 + bh] =
          op[(size_t)(row >> 4) * 16384 + (size_t)(c0 + (row & 15)) * 128 + bh];
    }
    // validate chunk 0, stage it, issue chunk 1
    while (v[0] == SENT || v[1] == SENT || v[2] == SENT || v[3] == SENT ||
           v[4] == SENT || v[5] == SENT || v[6] == SENT || v[7] == SENT) {
      __builtin_amdgcn_s_sleep(1);
      #pragma unroll
      for (int u = 0; u < 8; ++u)
        if (v[u] == SENT) v[u] = ald(Rin + u * 512 + tid);
    }
    #pragma unroll
    for (int u = 0; u < 8; ++u) RtPb[u * 512 + tid] = v[u];
    #pragma unroll
    for (int u = 0; u < 8; ++u) v[u] = ald(Rin + 4096 + u * 512 + tid);
    __syncthreads();
    double acc0 = 0.0, acc1 = 0.0, acc2 = 0.0, acc3 = 0.0;
    #pragma unroll
    for (int c = 0; c < 4; ++c) {
      // compute chunk c (loads for chunk c+1 already in flight)
      const double* rt = RtPb + (c & 1) * 4096;
      #pragma unroll
      for (int dl = 0; dl < 32; ++dl) {
        int d = c * 32 + dl;
        double rr = rt[dl * 128 + bh];
        acc0 += KA[(r2) * 128 + d] * rr;
        acc1 += KA[(r2 + 4) * 128 + d] * rr;
        acc2 += KA[(r2 + 8) * 128 + d] * rr;
        acc3 += KA[(r2 + 12) * 128 + d] * rr;
      }
      if (c < 3) {
        // validate c+1 (spin regs only), stage into the other buffer
        // (its previous readers -- chunk c-1 -- finished before the last barrier)
        while (v[0] == SENT || v[1] == SENT || v[2] == SENT || v[3] == SENT ||
               v[4] == SENT || v[5] == SENT || v[6] == SENT || v[7] == SENT) {
          __builtin_amdgcn_s_sleep(1);
          #pragma unroll
          for (int u = 0; u < 8; ++u)
            if (v[u] == SENT)
              v[u] = ald(Rin + (c + 1) * 4096 + u * 512 + tid);
        }
        double* rtn = RtPb + ((c + 1) & 1) * 4096;
        #pragma unroll
        for (int u = 0; u < 8; ++u) rtn[u * 512 + tid] = v[u];
        if (c < 2) {
          #pragma unroll
          for (int u = 0; u < 8; ++u)
            v[u] = ald(Rin + (c + 2) * 4096 + u * 512 + tid);
        }
      }
      __syncthreads();
    }
    // Pb aliases RtPb[0..2064): all chunk reads done (last barrier passed)
    Pb[(r2) * 129 + bh] = acc0;
    Pb[(r2 + 4) * 129 + bh] = acc1;
    Pb[(r2 + 8) * 129 + bh] = acc2;
    Pb[(r2 + 12) * 129 + bh] = acc3;
    __syncthreads();
    // stage B: all 512 threads; thread = (seg, aa, cc), 16 b's per seg
    {
      int aa = oi >> 4, cc = oi & 15, b0 = seg * 16;
      double s0 = 0.0, s1 = 0.0;
      #pragma unroll
      for (int j = 0; j < 4; ++j) {
        #pragma unroll
        for (int m = 0; m < 16; m += 2) {
          s0 += Pb[(j * 4 + aa) * 129 + b0 + m] * KC[(j * 16 + cc) * 129 + b0 + m];
          s1 += Pb[(j * 4 + aa) * 129 + b0 + m + 1] *
                KC[(j * 16 + cc) * 129 + b0 + m + 1];
        }
      }
      red[tid] = s0 + s1;
    }
    __syncthreads();
    if (tid < 64) {
      int aa = tid >> 4, cc = tid & 15;
      double o = ((red[tid] + red[tid + 64]) + (red[tid + 128] + red[tid + 192])) +
                 ((red[tid + 256] + red[tid + 320]) +
                  (red[tid + 384] + red[tid + 448]));
      double* outp = (p > 0) ? (Rodd + (size_t)(p - 1) * 16384) : Rs0;
      ast(&outp[(size_t)(a0 + aa) * 128 + c0 + cc], o);
      if (p == 0 && w == 0 && tid == 0) ast(Zp, o);
    }
    __syncthreads();
  }
}

// ---------------------------------------------------------------- pair sampler
// y_{ss'} = B_{ss'}^T w; Q_q = y_q^T R y_q. ps0_e = (Q2+Q3)/zn; ps0_o =
// Q_{2k_e+1}/(p_e*zn); w' = y_{2k_e+k_o}/sqrt(p_e*p_o*zn).
// NO min-waves clause: bf[128] floats must have the 256-VGPR budget (the
// (512,2) clause capped at 128 -> spill). Grid is 32 WGs; occupancy moot.
__global__ __launch_bounds__(512) void k_sample4(
    const double* __restrict__ Blo, const double* __restrict__ Bhi, int splitP,
    const double* __restrict__ Rodd, double* __restrict__ wbuf,
    const double* __restrict__ Zp, const float* __restrict__ randu,
    float* __restrict__ out) {
  __shared__ double Rl[16384];
  __shared__ double wl[128], yl[512], part[64], ctrl[2];
  const int g = blockIdx.x, tid = threadIdx.x;
  const int q = tid >> 7, c = tid & 127;
  const int lane = tid & 63, wv = tid >> 6;
  for (int p = g; p < 512; p += 32) {
    const double* Bb = (p < splitP) ? (Blo + (size_t)p * 65536)
                                    : (Bhi + (size_t)(p - splitP) * 65536);
    // prefetch B_q column c -> f32 regs (fully unrolled: static indices)
    float bf[128];
    {
      const double* bp = Bb + (size_t)q * 16384 + c;
      #pragma unroll
      for (int r = 0; r < 128; ++r) bf[r] = (float)bp[(size_t)r * 128];
    }
    // prefetch R -> LDS (R fully written: scan kernel completed before launch)
    {
      const double* Rp = Rodd + (size_t)p * 16384;
      #pragma unroll 4
      for (int u = 0; u < 32; ++u) Rl[u * 512 + tid] = Rp[u * 512 + tid];
    }
    // poll w (payload-is-flag)
    if (tid < 128) {
      double* wp = wbuf + (size_t)p * 128 + tid;
      double vv;
      while ((vv = ald(wp)) == SENT) __builtin_amdgcn_s_sleep(1);
      wl[tid] = vv;
    }
    __syncthreads();
    // matvec: y_q[c] = sum_r B_q[r][c] * w[r]  (4-way partial chains)
    {
      double a0 = 0.0, a1 = 0.0, a2 = 0.0, a3 = 0.0;
      #pragma unroll
      for (int r = 0; r < 128; r += 4) {
        a0 += (double)bf[r] * wl[r];
        a1 += (double)bf[r + 1] * wl[r + 1];
        a2 += (double)bf[r + 2] * wl[r + 2];
        a3 += (double)bf[r + 3] * wl[r + 3];
      }
      yl[q * 128 + c] = (a0 + a1) + (a2 + a3);
    }
    __syncthreads();
    // Q_q = sum_c y[c] * (sum_r R[r][c] y[r])  (R symmetric; 4-way partials)
    {
      double z0 = 0.0, z1 = 0.0, z2 = 0.0, z3 = 0.0;
      #pragma unroll
      for (int r = 0; r < 128; r += 4) {
        z0 += Rl[(r) * 128 + c] * yl[q * 128 + r];
        z1 += Rl[(r + 1) * 128 + c] * yl[q * 128 + r + 1];
        z2 += Rl[(r + 2) * 128 + c] * yl[q * 128 + r + 2];
        z3 += Rl[(r + 3) * 128 + c] * yl[q * 128 + r + 3];
      }
      double qp = ((z0 + z1) + (z2 + z3)) * yl[q * 128 + c];
      #pragma unroll
      for (int off = 1; off < 64; off <<= 1) qp += __shfl_xor(qp, off, 64);
      if (lane == 0) part[wv] = qp;
    }
    __syncthreads();
    if (tid == 0) {
      double Q1 = part[2] + part[3];
      double Q2 = part[4] + part[5], Q3 = part[6] + part[7];
      double zn = (p == 0) ? *Zp : 1.0;
      double ps0e = (Q2 + Q3) / zn;
      double ue = (double)randu[2 * p];
      bool t0e = ue < ps0e;
      double pe = t0e ? ps0e : (1.0 - ps0e);
      int ke = t0e ? 1 : 0;
      out[4 * p] = t0e ? 0.0f : 1.0f;
      out[4 * p + 1] = t0e ? 1.0f : 0.0f;
      double Qk1 = (ke == 1) ? Q3 : Q1;
      double ps0o = Qk1 / (pe * zn);
      double uo = (double)randu[2 * p + 1];
      bool t0o = uo < ps0o;
      double po = t0o ? ps0o : (1.0 - ps0o);
      int ko = t0o ? 1 : 0;
      out[4 * p + 2] = t0o ? 0.0f : 1.0f;
      out[4 * p + 3] = t0o ? 1.0f : 0.0f;
      ctrl[0] = (double)(ke * 2 + ko);
      ctrl[1] = 1.0 / sqrt(pe * po * zn);
    }
    __syncthreads();
    {
      int ksel = (int)ctrl[0];
      double sc = ctrl[1];
      if (tid < 128)
        ast(&wbuf[(size_t)(p + 1) * 128 + tid], yl[ksel * 128 + tid] * sc);
    }
    __syncthreads();
  }
}

// ---------------------------------------------------------------- legacy scan
template <typename TT, typename TR>
__global__ __launch_bounds__(512) void k_scan(const TT* __restrict__ Tk,
                                              TR* __restrict__ Rbuf,
                                              TR* __restrict__ Rs0,
                                              double* __restrict__ Zp) {
  __shared__ double KA[8 * 128];
  __shared__ double KC[16 * 129];
  __shared__ double Rt2[16 * 128];
  __shared__ double Pb[8 * 129];
  __shared__ double red[256];
  const int w = blockIdx.x, tid = threadIdx.x;
  const int a0 = (w >> 3) * 4, c0 = (w & 7) * 16;
  const int r2 = tid >> 7, bh = tid & 127;
  const TR SV = sentv<TR>();
  for (int i = NS - 1; i >= 0; --i) {
    const TT* K = Tk + (size_t)i * 32768;
    const TR* Rin = Rbuf + (size_t)i * 16384;
    double v[4];
    #pragma unroll
    for (int u = 0; u < 4; ++u) {
      TR t = aldT(Rin + tid * 4 + u);
      v[u] = (t == SV) ? SENT : (double)t;
    }
    for (int idx = tid; idx < 1024; idx += 512) {
      int row = idx >> 7, col = idx & 127;
      KA[idx] = (double)K[(size_t)((row >> 2) * 128 + a0 + (row & 3)) * 128 + col];
    }
    double kc[8];
    #pragma unroll
    for (int u = 0; u < 8; ++u) {
      int row = r2 + 4 * u;
      kc[u] = (double)K[(size_t)((row >> 4) * 128 + c0 + (row & 15)) * 128 + bh];
    }
    double acc0 = 0.0, acc1 = 0.0;
    for (int c = 0; c < 8; ++c) {
      while (v[0] == SENT || v[1] == SENT || v[2] == SENT || v[3] == SENT) {
        __builtin_amdgcn_s_sleep(1);
        #pragma unroll
        for (int u = 0; u < 4; ++u)
          if (v[u] == SENT) {
            TR t = aldT(Rin + c * 2048 + tid * 4 + u);
            v[u] = (t == SV) ? SENT : (double)t;
          }
      }
      {
        int base = tid * 4, dl = base >> 7, bb = base & 127;
        Rt2[dl * 128 + bb] = v[0];
        Rt2[dl * 128 + bb + 1] = v[1];
        Rt2[dl * 128 + bb + 2] = v[2];
        Rt2[dl * 128 + bb + 3] = v[3];
      }
      __syncthreads();
      if (c < 7) {
        #pragma unroll
        for (int u = 0; u < 4; ++u) {
          TR t = aldT(Rin + (c + 1) * 2048 + tid * 4 + u);
          v[u] = (t == SV) ? SENT : (double)t;
        }
      }
      #pragma unroll
      for (int dl = 0; dl < 16; ++dl) {
        int d = c * 16 + dl;
        double rr = Rt2[dl * 128 + bh];
        acc0 += KA[r2 * 128 + d] * rr;
        acc1 += KA[(r2 + 4) * 128 + d] * rr;
      }
      __syncthreads();
    }
    Pb[r2 * 129 + bh] = acc0;
    Pb[(r2 + 4) * 129 + bh] = acc1;
    __syncthreads();
    double s = 0.0;
    const int oi = tid & 63, seg = (tid >> 6) & 3;
    #pragma unroll
    for (int j = 0; j < 2; ++j) {
      #pragma unroll
      for (int t = 0; t < 4; ++t)
        KC[(r2 + 4 * t) * 129 + bh] = kc[j * 4 + t];
      __syncthreads();
      if (tid < 256) {
        int aa = oi >> 4, cc = oi & 15;
        double acc = 0.0;
        #pragma unroll
        for (int m = 0; m < 32; ++m) {
          int b = seg * 32 + m;
          acc += Pb[(j * 4 + aa) * 129 + b] * KC[cc * 129 + b];
        }
        s += acc;
      }
      __syncthreads();
    }
    if (tid < 256) red[tid] = s;
    __syncthreads();
    if (tid < 64) {
      int aa = tid >> 4, cc = tid & 15;
      double o = red[tid] + red[tid + 64] + red[tid + 128] + red[tid + 192];
      TR* outp = (i > 0) ? (Rbuf + (size_t)(i - 1) * 16384) : Rs0;
      ast(&outp[(size_t)(a0 + aa) * 128 + c0 + cc], (TR)o);
      if (i == 0 && w == 0 && tid == 0) ast(Zp, o);
    }
    __syncthreads();
  }
}

// ---------------------------------------------------------------- legacy sampling
template <typename TT, typename TR>
__global__ __launch_bounds__(1024) void k_sample(const TT* __restrict__ Tk,
                                                 const TR* __restrict__ Rbuf,
                                                 double* __restrict__ wbuf,
                                                 const double* __restrict__ Zp,
                                                 const float* __restrict__ randu,
                                                 float* __restrict__ out) {
  __shared__ double wl[128], yl[256], part[1024], ctrl[2];
  const int g = blockIdx.x, tid = threadIdx.x;
  const int s = tid >> 9, q = (tid >> 7) & 3, b = tid & 127;
  const int lane = tid & 63, wv = tid >> 6;
  using TR2 = typename V2<TR>::t;
  for (int site = g; site < NS; site += 16) {
    const TT* T = Tk + (size_t)site * 32768;
    double tf[32];
    {
      const TT* tp = T + ((size_t)s * 128 + q * 32) * 128 + b;
      #pragma unroll
      for (int t = 0; t < 32; ++t) tf[t] = (double)tp[(size_t)t * 128];
    }
    double rv[16];
    {
      const TR2* R2 = (const TR2*)(Rbuf + (size_t)site * 16384);
      #pragma unroll
      for (int t = 0; t < 8; ++t) {
        TR2 v = R2[t * 1024 + tid];
        rv[2 * t] = (double)v.x; rv[2 * t + 1] = (double)v.y;
      }
    }
    if (tid < 128) {
      double* wp = wbuf + (size_t)site * 128 + tid;
      double v;
      while ((v = ald(wp)) == SENT) __builtin_amdgcn_s_sleep(1);
      wl[tid] = v;
    }
    __syncthreads();
    {
      double p0 = 0.0;
      #pragma unroll
      for (int t = 0; t < 32; ++t) p0 += tf[t] * wl[q * 32 + t];
      part[(s * 4 + q) * 128 + b] = p0;
    }
    __syncthreads();
    if (tid < 256) {
      int ss = tid >> 7, bb = tid & 127;
      yl[ss * 128 + bb] = part[(ss * 4) * 128 + bb] + part[(ss * 4 + 1) * 128 + bb] +
                          part[(ss * 4 + 2) * 128 + bb] + part[(ss * 4 + 3) * 128 + bb];
    }
    __syncthreads();
    {
      double y1a = yl[128 + 2 * lane], y1b = yl[128 + 2 * lane + 1];
      double vp = 0.0;
      #pragma unroll
      for (int t = 0; t < 8; ++t)
        vp += yl[128 + 16 * t + wv] * (rv[2 * t] * y1a + rv[2 * t + 1] * y1b);
      #pragma unroll
      for (int off = 1; off < 64; off <<= 1) vp += __shfl_xor(vp, off, 64);
      if (lane == 0) part[wv] = vp;
    }
    __syncthreads();
    if (tid == 0) {
      double v = 0.0;
      #pragma unroll
      for (int k = 0; k < 16; ++k) v += part[k];
      double zn = (site == 0) ? *Zp : 1.0;
      double ps0 = v / zn;
      double u = (double)randu[site];
      bool take0 = u < ps0;
      double pp = take0 ? ps0 : (1.0 - ps0);
      ctrl[0] = take0 ? 1.0 : 0.0;
      ctrl[1] = 1.0 / sqrt(pp * zn);
      out[2 * site] = take0 ? 0.0f : 1.0f;
      out[2 * site + 1] = take0 ? 1.0f : 0.0f;
    }
    __syncthreads();
    {
      int k = (ctrl[0] != 0.0) ? 1 : 0;
      double sc = ctrl[1];
      if (tid < 128)
        ast(&wbuf[(size_t)(site + 1) * 128 + tid], yl[k * 128 + tid] * sc);
    }
    __syncthreads();
  }
}

// ---------------------------------------------------------------- diagnostics
__global__ void k_diag(float* __restrict__ out, int n, float mb) {
  int i = blockIdx.x * blockDim.x + threadIdx.x;
  if (i < n) out[i] = (i == 0) ? mb : ((i & 1) ? 0.75f : 0.25f);
}

// ---------------------------------------------------------------- plans
template <typename TT, typename TR>
struct Plan {
  size_t oTk, oR, oRs0, oW, oZ, need;
  Plan() {
    oTk = 0;
    oR = oTk + sizeof(TT) * (size_t)NS * 32768;
    oRs0 = oR + sizeof(TR) * (size_t)NS * 16384;
    oW = oRs0 + sizeof(TR) * 16384;
    oZ = oW + 8ull * (NS + 1) * 128;
    need = oZ + 64;
  }
};

template <typename TT>
struct PlanN {
  size_t oTk, oScr, oR, oRs0, oW, oZ, need;
  int splitP;
  PlanN() {
    splitP = (sizeof(TT) == 8) ? 256 : 128;
    oTk = 0;
    size_t tkB = sizeof(TT) * (size_t)NS * 32768;
    oScr = tkB;
    size_t yB = 8ull * NS * 16384;
    size_t bhiB = 8ull * (size_t)(512 - splitP) * 4 * 16384;
    size_t scrB = (yB > bhiB) ? yB : bhiB;
    oR = oScr + scrB;
    oRs0 = oR + 8ull * 512 * 16384;
    oW = oRs0 + 8ull * 16384;
    oZ = oW + 8ull * 513 * 128;
    need = oZ + 64;
  }
};

template <typename TT, typename TR>
static void run_cfg(const float* params, const float* randu, float* out,
                    char* ws, hipStream_t stream) {
  Plan<TT, TR> P;
  TT* Tk = (TT*)(ws + P.oTk);
  TR* Rbuf = (TR*)(ws + P.oR);
  TR* Yscr = Rbuf;
  TR* Rs0 = (TR*)(ws + P.oRs0);
  double* wbuf = (double*)(ws + P.oW);
  double* Zp = (double*)(ws + P.oZ);
  k_cayley<TT, TR><<<dim3(NS), dim3(256), 0, stream>>>(params, Tk, Yscr);
  k_w2<TT, TR><<<dim3(NS), dim3(256), 0, stream>>>(params, Yscr, Tk);
  k_init<TR><<<dim3(4096), dim3(256), 0, stream>>>(wbuf, Rbuf);
  k_scan<TT, TR><<<dim3(256), dim3(512), 0, stream>>>(Tk, Rbuf, Rs0, Zp);
  k_sample<TT, TR><<<dim3(16), dim3(1024), 0, stream>>>(Tk, Rbuf, wbuf, Zp, randu, out);
}

template <typename TT>
static void run_pairN(const float* params, const float* randu, float* out,
                      char* ws, hipStream_t stream) {
  PlanN<TT> P;
  TT* Tk = (TT*)(ws + P.oTk);
  double* Yscr = (double*)(ws + P.oScr);
  double* Bhi = (double*)(ws + P.oScr);
  double* Blo = (double*)(ws + P.oTk + sizeof(TT) * (size_t)512 * 32768);
  double* Rodd = (double*)(ws + P.oR);
  double* Rs0 = (double*)(ws + P.oRs0);
  double* wbuf = (double*)(ws + P.oW);
  double* Zp = (double*)(ws + P.oZ);
  const int sp = P.splitP;
  k_cayley<TT, double><<<dim3(NS), dim3(256), 0, stream>>>(params, Tk, Yscr);
  k_w2<TT, double><<<dim3(NS), dim3(256), 0, stream>>>(params, Yscr, Tk);
  k_init2<<<dim3(2048), dim3(256), 0, stream>>>(wbuf, Rodd);
  k_pair2<TT><<<dim3((512 - sp) * 4), dim3(256), 0, stream>>>(Tk, Bhi, sp);
  k_pair2<TT><<<dim3(sp * 4), dim3(256), 0, stream>>>(Tk, Blo, 0);
  k_scan3<<<dim3(256), dim3(512), 0, stream>>>(Blo, Bhi, sp, Rodd, Rs0, Zp);
  k_sample4<<<dim3(32), dim3(512), 0, stream>>>(Blo, Bhi, sp, Rodd, wbuf, Zp,
                                                randu, out);
}

extern "C" void kernel_launch(void* const* d_in, const int* in_sizes, int n_in,
                              void* d_out, int out_size, void* d_ws, size_t ws_size,
                              hipStream_t stream) {
  const float* params = (const float*)d_in[0];
  const float* randu = (const float*)d_in[1];
  float* out = (float*)d_out;
  char* ws = (char*)d_ws;
  if (ws_size >= PlanN<double>().need) {
    run_pairN<double>(params, randu, out, ws, stream);
  } else if (ws_size >= PlanN<float>().need) {
    run_pairN<float>(params, randu, out, ws, stream);
  } else if (ws_size >= Plan<double, double>().need) {
    run_cfg<double, double>(params, randu, out, ws, stream);
  } else if (ws_size >= Plan<float, double>().need) {
    run_cfg<float, double>(params, randu, out, ws, stream);
  } else if (ws_size >= Plan<float, float>().need) {
    run_cfg<float, float>(params, randu, out, ws, stream);
  } else {
    k_diag<<<dim3((out_size + 255) / 256), dim3(256), 0, stream>>>(
        out, out_size, (float)(ws_size >> 20));
  }
}

// Round 6
// 15284.048 us; speedup vs baseline: 7.2944x; 7.2944x over previous
//
#include <hip/hip_runtime.h>
#include <math.h>

#define NS 1024
#define SENT (-1.0e300)

template <typename T> struct V2;
template <> struct V2<double> { using t = double2; };
template <> struct V2<float>  { using t = float2; };

template <typename T> __device__ __forceinline__ T sentv();
template <> __device__ __forceinline__ double sentv<double>() { return -1.0e300; }
template <> __device__ __forceinline__ float  sentv<float>()  { return -3.0e38f; }

template <typename T>
__device__ __forceinline__ T aldT(const T* p) {
  return __hip_atomic_load(p, __ATOMIC_RELAXED, __HIP_MEMORY_SCOPE_AGENT);
}
__device__ __forceinline__ double ald(const double* p) {
  return __hip_atomic_load(p, __ATOMIC_RELAXED, __HIP_MEMORY_SCOPE_AGENT);
}
template <typename T>
__device__ __forceinline__ void ast(T* p, T v) {
  __hip_atomic_store(p, v, __ATOMIC_RELAXED, __HIP_MEMORY_SCOPE_AGENT);
}

// ---------------------------------------------------------------- init (legacy)
template <typename TR>
__global__ void k_init(double* __restrict__ wbuf, TR* __restrict__ Rbuf) {
  size_t stride = (size_t)gridDim.x * blockDim.x;
  size_t t = (size_t)blockIdx.x * blockDim.x + threadIdx.x;
  for (size_t idx = t; idx < (size_t)(NS + 1) * 128; idx += stride)
    wbuf[idx] = (idx < 128) ? ((idx == 0) ? 1.0 : 0.0) : SENT;
  const size_t lastoff = (size_t)(NS - 1) * 16384;
  for (size_t idx = t; idx < (size_t)NS * 16384; idx += stride)
    Rbuf[idx] = (idx < lastoff) ? sentv<TR>()
                                : (TR)((idx == lastoff) ? 1.0f : 0.0f);
}

// ---------------------------------------------------------------- init (pair plan)
__global__ void k_init2(double* __restrict__ wbuf, double* __restrict__ Rodd) {
  size_t stride = (size_t)gridDim.x * blockDim.x;
  size_t t = (size_t)blockIdx.x * blockDim.x + threadIdx.x;
  for (size_t idx = t; idx < (size_t)513 * 128; idx += stride)
    wbuf[idx] = (idx < 128) ? ((idx == 0) ? 1.0 : 0.0) : SENT;
  const size_t lastoff = (size_t)511 * 16384;
  for (size_t idx = t; idx < (size_t)512 * 16384; idx += stride)
    Rodd[idx] = (idx < lastoff) ? SENT : ((idx == lastoff) ? 1.0 : 0.0);
}

// ---------------------------------------------------------------- cayley
template <typename TT, typename TR>
__global__ __launch_bounds__(256) void k_cayley(const float* __restrict__ params,
                                                TT* __restrict__ Tk,
                                                TR* __restrict__ Yscr) {
  __shared__ float XB[64 * 132];
  __shared__ double prow[128], fcol[128];
  const int site = blockIdx.x, tid = threadIdx.x;
  const float* X = params + (size_t)site * 256 * 128;
  const int ti = tid >> 4, tj = tid & 15;
  const int R0 = ti * 8, C0 = tj * 8;
  double g[8][8];
  #pragma unroll
  for (int i = 0; i < 8; ++i)
    #pragma unroll
    for (int j = 0; j < 8; ++j) g[i][j] = ((R0 + i) == (C0 + j)) ? 1.0 : 0.0;
  for (int h = 0; h < 2; ++h) {
    for (int idx = tid; idx < 64 * 128; idx += 256) {
      int rr = idx >> 7, c = idx & 127;
      XB[rr * 132 + c] = X[(size_t)(h * 64 + rr) * 128 + c];
    }
    __syncthreads();
    int lo = h * 64;
    if ((R0 >> 6) == h) {
      #pragma unroll
      for (int i = 0; i < 8; ++i)
        #pragma unroll
        for (int j = 0; j < 8; ++j)
          g[i][j] += 0.5 * (double)XB[(R0 + i - lo) * 132 + (C0 + j)];
    }
    if ((C0 >> 6) == h) {
      #pragma unroll
      for (int i = 0; i < 8; ++i)
        #pragma unroll
        for (int j = 0; j < 8; ++j)
          g[i][j] -= 0.5 * (double)XB[(C0 + j - lo) * 132 + (R0 + i)];
    }
    __syncthreads();
  }
  for (int h = 0; h < 2; ++h) {
    for (int idx = tid; idx < 64 * 128; idx += 256) {
      int rr = idx >> 7, c = idx & 127;
      XB[rr * 132 + c] = X[(size_t)(128 + h * 64 + rr) * 128 + c];
    }
    __syncthreads();
    for (int a = 0; a < 64; ++a) {
      double fa[8], fb[8];
      #pragma unroll
      for (int i = 0; i < 8; ++i) fa[i] = 0.5 * (double)XB[a * 132 + R0 + i];
      #pragma unroll
      for (int j = 0; j < 8; ++j) fb[j] = 0.5 * (double)XB[a * 132 + C0 + j];
      #pragma unroll
      for (int i = 0; i < 8; ++i)
        #pragma unroll
        for (int j = 0; j < 8; ++j) g[i][j] += fa[i] * fb[j];
    }
    __syncthreads();
  }
  for (int p = 0; p < 128; ++p) {
    int pb = p >> 3, pl = p & 7;
    if (ti == pb) {
      #pragma unroll
      for (int j = 0; j < 8; ++j) prow[C0 + j] = g[pl][j];
    }
    if (tj == pb) {
      #pragma unroll
      for (int i = 0; i < 8; ++i) fcol[R0 + i] = g[i][pl];
    }
    __syncthreads();
    double d = 1.0 / prow[p];
    double pd[8];
    #pragma unroll
    for (int j = 0; j < 8; ++j) pd[j] = prow[C0 + j] * d;
    #pragma unroll
    for (int i = 0; i < 8; ++i) {
      int r = R0 + i;
      if (r == p) {
        #pragma unroll
        for (int j = 0; j < 8; ++j) g[i][j] = ((C0 + j) == p) ? d : pd[j];
      } else {
        double f = fcol[r];
        #pragma unroll
        for (int j = 0; j < 8; ++j)
          g[i][j] = ((C0 + j) == p) ? (-f * d) : (g[i][j] - f * pd[j]);
      }
    }
    __syncthreads();
  }
  TR* Ys = Yscr + (size_t)site * 16384;
  TT* Ts = Tk + (size_t)site * 32768;
  #pragma unroll
  for (int i = 0; i < 8; ++i) {
    int r = R0 + i, s = r & 1, a = r >> 1;
    #pragma unroll
    for (int j = 0; j < 8; ++j) {
      int c = C0 + j;
      Ys[(size_t)r * 128 + c] = (TR)g[i][j];
      Ts[((size_t)s * 128 + a) * 128 + c] =
          (TT)(2.0 * g[i][j] - ((r == c) ? 1.0 : 0.0));
    }
  }
}

// ---------------------------------------------------------------- W_bot = -X2 * Y
template <typename TT, typename TR>
__global__ __launch_bounds__(256) void k_w2(const float* __restrict__ params,
                                            const TR* __restrict__ Yscr,
                                            TT* __restrict__ Tk) {
  __shared__ float X2c[16 * 132];
  __shared__ double Yt[16 * 130];
  const int site = blockIdx.x, tid = threadIdx.x;
  const float* X2g = params + (size_t)site * 256 * 128 + 128 * 128;
  const TR* Ys = Yscr + (size_t)site * 16384;
  TT* Ts = Tk + (size_t)site * 32768;
  const int ti = tid >> 4, tj = tid & 15;
  const int R0 = ti * 8, C0 = tj * 8;
  double acc[8][8];
  #pragma unroll
  for (int i = 0; i < 8; ++i)
    #pragma unroll
    for (int j = 0; j < 8; ++j) acc[i][j] = 0.0;
  for (int b0 = 0; b0 < 128; b0 += 16) {
    __syncthreads();
    for (int idx = tid; idx < 2048; idx += 256) {
      int r = idx >> 4, bb = idx & 15;
      X2c[bb * 132 + r] = X2g[(size_t)r * 128 + b0 + bb];
    }
    for (int idx = tid; idx < 2048; idx += 256) {
      int bb = idx >> 7, c = idx & 127;
      Yt[bb * 130 + c] = (double)Ys[(size_t)(b0 + bb) * 128 + c];
    }
    __syncthreads();
    for (int bb = 0; bb < 16; ++bb) {
      double xf[8], yf[8];
      #pragma unroll
      for (int i = 0; i < 8; ++i) xf[i] = (double)X2c[bb * 132 + R0 + i];
      #pragma unroll
      for (int j = 0; j < 8; ++j) yf[j] = Yt[bb * 130 + C0 + j];
      #pragma unroll
      for (int i = 0; i < 8; ++i)
        #pragma unroll
        for (int j = 0; j < 8; ++j) acc[i][j] += xf[i] * yf[j];
    }
  }
  #pragma unroll
  for (int i = 0; i < 8; ++i) {
    int r = 128 + R0 + i, s = r & 1, a = r >> 1;
    #pragma unroll
    for (int j = 0; j < 8; ++j)
      Ts[((size_t)s * 128 + a) * 128 + C0 + j] = (TT)(-acc[i][j]);
  }
}

// ---------------------------------------------------------------- pair Kraus ops
template <typename TT>
__global__ __launch_bounds__(256) void k_pair2(const TT* __restrict__ Tk,
                                               double* __restrict__ outB,
                                               int pair0) {
  __shared__ double As[16 * 136];
  __shared__ double Bs[16 * 132];
  const int blk = blockIdx.x, tid = threadIdx.x;
  const int pl = blk >> 2, q = blk & 3, s = q >> 1, sp = q & 1;
  const int p = pair0 + pl;
  const TT* A = Tk + ((size_t)(2 * p) * 2 + s) * 16384;
  const TT* B = Tk + ((size_t)(2 * p + 1) * 2 + sp) * 16384;
  double* outp = outB + (size_t)pl * 65536 + (size_t)q * 16384;
  const int ti = tid >> 4, tj = tid & 15, R0 = ti * 8, C0 = tj * 8;
  double acc[8][8];
  #pragma unroll
  for (int i = 0; i < 8; ++i)
    #pragma unroll
    for (int j = 0; j < 8; ++j) acc[i][j] = 0.0;
  for (int b0 = 0; b0 < 128; b0 += 16) {
    __syncthreads();
    for (int idx = tid; idx < 2048; idx += 256) {
      int r = idx >> 4, bb = idx & 15;
      As[bb * 136 + r] = (double)A[(size_t)r * 128 + b0 + bb];
    }
    for (int idx = tid; idx < 2048; idx += 256) {
      int bb = idx >> 7, c = idx & 127;
      Bs[bb * 132 + c] = (double)B[(size_t)(b0 + bb) * 128 + c];
    }
    __syncthreads();
    for (int bb = 0; bb < 16; ++bb) {
      double fa[8], fb[8];
      #pragma unroll
      for (int i = 0; i < 8; ++i) fa[i] = As[bb * 136 + R0 + i];
      #pragma unroll
      for (int j = 0; j < 8; ++j) fb[j] = Bs[bb * 132 + C0 + j];
      #pragma unroll
      for (int i = 0; i < 8; ++i)
        #pragma unroll
        for (int j = 0; j < 8; ++j) acc[i][j] += fa[i] * fb[j];
    }
  }
  #pragma unroll
  for (int i = 0; i < 8; ++i)
    #pragma unroll
    for (int j = 0; j < 8; ++j)
      outp[(size_t)(R0 + i) * 128 + C0 + j] = acc[i][j];
}

// ---------------------------------------------------------------- pair-composed scan
// EXACT round-2 structure (verified: VGPR 68, no scratch, 7.78 ms) with ONE
// change: load/store indexing tid*4+u -> u*512+tid (coalesced global loads,
// conflict-free Rt stores; r3/r4 proved this layout gives 0 LDS conflicts).
// Rounds 3/4 (v[32]/v[8]+unrolled pipeline) spilled at the 128-VGPR cap ->
// 200 GB scratch churn. Do NOT widen the in-flight register window.
__global__ __launch_bounds__(512, 2) void k_scan3(const double* __restrict__ Blo,
                                                  const double* __restrict__ Bhi,
                                                  int splitP,
                                                  double* __restrict__ Rodd,
                                                  double* __restrict__ Rs0,
                                                  double* __restrict__ Zp) {
  __shared__ double KA[16 * 128];   // a-rows (j,aa): row = j*4+aa
  __shared__ double KC[16 * 129];   // one j's 16 c-rows (staged from kc regs)
  __shared__ double Rt[16 * 128];   // 16-d-row chunk of R
  __shared__ double Pb[16 * 129];   // stage-A output
  __shared__ double red[256];
  const int w = blockIdx.x, tid = threadIdx.x;
  const int a0 = (w >> 3) * 4, c0 = (w & 7) * 16;
  const int r2 = tid >> 7, bh = tid & 127;
  for (int p = 511; p >= 0; --p) {
    const double* op = (p < splitP) ? (Blo + (size_t)p * 65536)
                                    : (Bhi + (size_t)(p - splitP) * 65536);
    const double* Rin = Rodd + (size_t)p * 16384;
    // prefetch chunk 0 (coalesced: u*512+tid)
    double v[4];
    #pragma unroll
    for (int u = 0; u < 4; ++u) v[u] = ald(Rin + u * 512 + tid);
    // KA -> LDS
    for (int idx = tid; idx < 2048; idx += 512) {
      int row = idx >> 7, col = idx & 127;
      KA[idx] =
          op[(size_t)(row >> 2) * 16384 + (size_t)(a0 + (row & 3)) * 128 + col];
    }
    // KC source rows (4 j's x 16 c-rows) -> registers
    double kc[16];
    #pragma unroll
    for (int u = 0; u < 16; ++u) {
      int row = r2 + 4 * u;
      kc[u] = op[(size_t)(row >> 4) * 16384 + (size_t)(c0 + (row & 15)) * 128 + bh];
    }
    double acc0 = 0.0, acc1 = 0.0, acc2 = 0.0, acc3 = 0.0;
    for (int c = 0; c < 8; ++c) {
      while (v[0] == SENT || v[1] == SENT || v[2] == SENT || v[3] == SENT) {
        __builtin_amdgcn_s_sleep(1);
        #pragma unroll
        for (int u = 0; u < 4; ++u)
          if (v[u] == SENT) v[u] = ald(Rin + c * 2048 + u * 512 + tid);
      }
      #pragma unroll
      for (int u = 0; u < 4; ++u) Rt[u * 512 + tid] = v[u];
      __syncthreads();
      if (c < 7) {
        #pragma unroll
        for (int u = 0; u < 4; ++u)
          v[u] = ald(Rin + (c + 1) * 2048 + u * 512 + tid);
      }
      #pragma unroll
      for (int dl = 0; dl < 16; ++dl) {
        int d = c * 16 + dl;
        double rr = Rt[dl * 128 + bh];
        acc0 += KA[(r2) * 128 + d] * rr;
        acc1 += KA[(r2 + 4) * 128 + d] * rr;
        acc2 += KA[(r2 + 8) * 128 + d] * rr;
        acc3 += KA[(r2 + 12) * 128 + d] * rr;
      }
      __syncthreads();
    }
    Pb[(r2) * 129 + bh] = acc0;
    Pb[(r2 + 4) * 129 + bh] = acc1;
    Pb[(r2 + 8) * 129 + bh] = acc2;
    Pb[(r2 + 12) * 129 + bh] = acc3;
    __syncthreads();
    // stage B: four j passes through the 16-row KC buffer
    double s = 0.0;
    const int oi = tid & 63, seg = (tid >> 6) & 3;
    #pragma unroll
    for (int j = 0; j < 4; ++j) {
      #pragma unroll
      for (int t = 0; t < 4; ++t)
        KC[(r2 + 4 * t) * 129 + bh] = kc[j * 4 + t];
      __syncthreads();
      if (tid < 256) {
        int aa = oi >> 4, cc = oi & 15;
        double acc = 0.0;
        #pragma unroll
        for (int m = 0; m < 32; ++m) {
          int b = seg * 32 + m;
          acc += Pb[(j * 4 + aa) * 129 + b] * KC[cc * 129 + b];
        }
        s += acc;
      }
      __syncthreads();
    }
    if (tid < 256) red[tid] = s;
    __syncthreads();
    if (tid < 64) {
      int aa = tid >> 4, cc = tid & 15;
      double o = red[tid] + red[tid + 64] + red[tid + 128] + red[tid + 192];
      double* outp = (p > 0) ? (Rodd + (size_t)(p - 1) * 16384) : Rs0;
      ast(&outp[(size_t)(a0 + aa) * 128 + c0 + cc], o);
      if (p == 0 && w == 0 && tid == 0) ast(Zp, o);
    }
    __syncthreads();
  }
}

// ---------------------------------------------------------------- pair sampler
// y_{ss'} = B_{ss'}^T w; Q_q = y_q^T R y_q. ps0_e = (Q2+Q3)/zn; ps0_o =
// Q_{2k_e+1}/(p_e*zn); w' = y_{2k_e+k_o}/sqrt(p_e*p_o*zn).
// NO min-waves clause: bf[128] needs the full 256-VGPR budget (a (512,2)
// clause caps at 128 -> spill). Grid is 32 WGs; occupancy moot.
__global__ __launch_bounds__(512) void k_sample4(
    const double* __restrict__ Blo, const double* __restrict__ Bhi, int splitP,
    const double* __restrict__ Rodd, double* __restrict__ wbuf,
    const double* __restrict__ Zp, const float* __restrict__ randu,
    float* __restrict__ out) {
  __shared__ double Rl[16384];
  __shared__ double wl[128], yl[512], part[64], ctrl[2];
  const int g = blockIdx.x, tid = threadIdx.x;
  const int q = tid >> 7, c = tid & 127;
  const int lane = tid & 63, wv = tid >> 6;
  for (int p = g; p < 512; p += 32) {
    const double* Bb = (p < splitP) ? (Blo + (size_t)p * 65536)
                                    : (Bhi + (size_t)(p - splitP) * 65536);
    // prefetch B_q column c -> f32 regs (fully unrolled: static indices)
    float bf[128];
    {
      const double* bp = Bb + (size_t)q * 16384 + c;
      #pragma unroll
      for (int r = 0; r < 128; ++r) bf[r] = (float)bp[(size_t)r * 128];
    }
    // prefetch R -> LDS (R fully written: scan kernel completed before launch)
    {
      const double* Rp = Rodd + (size_t)p * 16384;
      #pragma unroll 4
      for (int u = 0; u < 32; ++u) Rl[u * 512 + tid] = Rp[u * 512 + tid];
    }
    // poll w (payload-is-flag)
    if (tid < 128) {
      double* wp = wbuf + (size_t)p * 128 + tid;
      double vv;
      while ((vv = ald(wp)) == SENT) __builtin_amdgcn_s_sleep(1);
      wl[tid] = vv;
    }
    __syncthreads();
    // matvec: y_q[c] = sum_r B_q[r][c] * w[r]  (4-way partial chains)
    {
      double a0 = 0.0, a1 = 0.0, a2 = 0.0, a3 = 0.0;
      #pragma unroll
      for (int r = 0; r < 128; r += 4) {
        a0 += (double)bf[r] * wl[r];
        a1 += (double)bf[r + 1] * wl[r + 1];
        a2 += (double)bf[r + 2] * wl[r + 2];
        a3 += (double)bf[r + 3] * wl[r + 3];
      }
      yl[q * 128 + c] = (a0 + a1) + (a2 + a3);
    }
    __syncthreads();
    // Q_q = sum_c y[c] * (sum_r R[r][c] y[r])  (R symmetric; 4-way partials)
    {
      double z0 = 0.0, z1 = 0.0, z2 = 0.0, z3 = 0.0;
      #pragma unroll
      for (int r = 0; r < 128; r += 4) {
        z0 += Rl[(r) * 128 + c] * yl[q * 128 + r];
        z1 += Rl[(r + 1) * 128 + c] * yl[q * 128 + r + 1];
        z2 += Rl[(r + 2) * 128 + c] * yl[q * 128 + r + 2];
        z3 += Rl[(r + 3) * 128 + c] * yl[q * 128 + r + 3];
      }
      double qp = ((z0 + z1) + (z2 + z3)) * yl[q * 128 + c];
      #pragma unroll
      for (int off = 1; off < 64; off <<= 1) qp += __shfl_xor(qp, off, 64);
      if (lane == 0) part[wv] = qp;
    }
    __syncthreads();
    if (tid == 0) {
      double Q1 = part[2] + part[3];
      double Q2 = part[4] + part[5], Q3 = part[6] + part[7];
      double zn = (p == 0) ? *Zp : 1.0;
      double ps0e = (Q2 + Q3) / zn;
      double ue = (double)randu[2 * p];
      bool t0e = ue < ps0e;
      double pe = t0e ? ps0e : (1.0 - ps0e);
      int ke = t0e ? 1 : 0;
      out[4 * p] = t0e ? 0.0f : 1.0f;
      out[4 * p + 1] = t0e ? 1.0f : 0.0f;
      double Qk1 = (ke == 1) ? Q3 : Q1;
      double ps0o = Qk1 / (pe * zn);
      double uo = (double)randu[2 * p + 1];
      bool t0o = uo < ps0o;
      double po = t0o ? ps0o : (1.0 - ps0o);
      int ko = t0o ? 1 : 0;
      out[4 * p + 2] = t0o ? 0.0f : 1.0f;
      out[4 * p + 3] = t0o ? 1.0f : 0.0f;
      ctrl[0] = (double)(ke * 2 + ko);
      ctrl[1] = 1.0 / sqrt(pe * po * zn);
    }
    __syncthreads();
    {
      int ksel = (int)ctrl[0];
      double sc = ctrl[1];
      if (tid < 128)
        ast(&wbuf[(size_t)(p + 1) * 128 + tid], yl[ksel * 128 + tid] * sc);
    }
    __syncthreads();
  }
}

// ---------------------------------------------------------------- legacy scan
template <typename TT, typename TR>
__global__ __launch_bounds__(512) void k_scan(const TT* __restrict__ Tk,
                                              TR* __restrict__ Rbuf,
                                              TR* __restrict__ Rs0,
                                              double* __restrict__ Zp) {
  __shared__ double KA[8 * 128];
  __shared__ double KC[16 * 129];
  __shared__ double Rt2[16 * 128];
  __shared__ double Pb[8 * 129];
  __shared__ double red[256];
  const int w = blockIdx.x, tid = threadIdx.x;
  const int a0 = (w >> 3) * 4, c0 = (w & 7) * 16;
  const int r2 = tid >> 7, bh = tid & 127;
  const TR SV = sentv<TR>();
  for (int i = NS - 1; i >= 0; --i) {
    const TT* K = Tk + (size_t)i * 32768;
    const TR* Rin = Rbuf + (size_t)i * 16384;
    double v[4];
    #pragma unroll
    for (int u = 0; u < 4; ++u) {
      TR t = aldT(Rin + tid * 4 + u);
      v[u] = (t == SV) ? SENT : (double)t;
    }
    for (int idx = tid; idx < 1024; idx += 512) {
      int row = idx >> 7, col = idx & 127;
      KA[idx] = (double)K[(size_t)((row >> 2) * 128 + a0 + (row & 3)) * 128 + col];
    }
    double kc[8];
    #pragma unroll
    for (int u = 0; u < 8; ++u) {
      int row = r2 + 4 * u;
      kc[u] = (double)K[(size_t)((row >> 4) * 128 + c0 + (row & 15)) * 128 + bh];
    }
    double acc0 = 0.0, acc1 = 0.0;
    for (int c = 0; c < 8; ++c) {
      while (v[0] == SENT || v[1] == SENT || v[2] == SENT || v[3] == SENT) {
        __builtin_amdgcn_s_sleep(1);
        #pragma unroll
        for (int u = 0; u < 4; ++u)
          if (v[u] == SENT) {
            TR t = aldT(Rin + c * 2048 + tid * 4 + u);
            v[u] = (t == SV) ? SENT : (double)t;
          }
      }
      {
        int base = tid * 4, dl = base >> 7, bb = base & 127;
        Rt2[dl * 128 + bb] = v[0];
        Rt2[dl * 128 + bb + 1] = v[1];
        Rt2[dl * 128 + bb + 2] = v[2];
        Rt2[dl * 128 + bb + 3] = v[3];
      }
      __syncthreads();
      if (c < 7) {
        #pragma unroll
        for (int u = 0; u < 4; ++u) {
          TR t = aldT(Rin + (c + 1) * 2048 + tid * 4 + u);
          v[u] = (t == SV) ? SENT : (double)t;
        }
      }
      #pragma unroll
      for (int dl = 0; dl < 16; ++dl) {
        int d = c * 16 + dl;
        double rr = Rt2[dl * 128 + bh];
        acc0 += KA[r2 * 128 + d] * rr;
        acc1 += KA[(r2 + 4) * 128 + d] * rr;
      }
      __syncthreads();
    }
    Pb[r2 * 129 + bh] = acc0;
    Pb[(r2 + 4) * 129 + bh] = acc1;
    __syncthreads();
    double s = 0.0;
    const int oi = tid & 63, seg = (tid >> 6) & 3;
    #pragma unroll
    for (int j = 0; j < 2; ++j) {
      #pragma unroll
      for (int t = 0; t < 4; ++t)
        KC[(r2 + 4 * t) * 129 + bh] = kc[j * 4 + t];
      __syncthreads();
      if (tid < 256) {
        int aa = oi >> 4, cc = oi & 15;
        double acc = 0.0;
        #pragma unroll
        for (int m = 0; m < 32; ++m) {
          int b = seg * 32 + m;
          acc += Pb[(j * 4 + aa) * 129 + b] * KC[cc * 129 + b];
        }
        s += acc;
      }
      __syncthreads();
    }
    if (tid < 256) red[tid] = s;
    __syncthreads();
    if (tid < 64) {
      int aa = tid >> 4, cc = tid & 15;
      double o = red[tid] + red[tid + 64] + red[tid + 128] + red[tid + 192];
      TR* outp = (i > 0) ? (Rbuf + (size_t)(i - 1) * 16384) : Rs0;
      ast(&outp[(size_t)(a0 + aa) * 128 + c0 + cc], (TR)o);
      if (i == 0 && w == 0 && tid == 0) ast(Zp, o);
    }
    __syncthreads();
  }
}

// ---------------------------------------------------------------- legacy sampling
template <typename TT, typename TR>
__global__ __launch_bounds__(1024) void k_sample(const TT* __restrict__ Tk,
                                                 const TR* __restrict__ Rbuf,
                                                 double* __restrict__ wbuf,
                                                 const double* __restrict__ Zp,
                                                 const float* __restrict__ randu,
                                                 float* __restrict__ out) {
  __shared__ double wl[128], yl[256], part[1024], ctrl[2];
  const int g = blockIdx.x, tid = threadIdx.x;
  const int s = tid >> 9, q = (tid >> 7) & 3, b = tid & 127;
  const int lane = tid & 63, wv = tid >> 6;
  using TR2 = typename V2<TR>::t;
  for (int site = g; site < NS; site += 16) {
    const TT* T = Tk + (size_t)site * 32768;
    double tf[32];
    {
      const TT* tp = T + ((size_t)s * 128 + q * 32) * 128 + b;
      #pragma unroll
      for (int t = 0; t < 32; ++t) tf[t] = (double)tp[(size_t)t * 128];
    }
    double rv[16];
    {
      const TR2* R2 = (const TR2*)(Rbuf + (size_t)site * 16384);
      #pragma unroll
      for (int t = 0; t < 8; ++t) {
        TR2 v = R2[t * 1024 + tid];
        rv[2 * t] = (double)v.x; rv[2 * t + 1] = (double)v.y;
      }
    }
    if (tid < 128) {
      double* wp = wbuf + (size_t)site * 128 + tid;
      double v;
      while ((v = ald(wp)) == SENT) __builtin_amdgcn_s_sleep(1);
      wl[tid] = v;
    }
    __syncthreads();
    {
      double p0 = 0.0;
      #pragma unroll
      for (int t = 0; t < 32; ++t) p0 += tf[t] * wl[q * 32 + t];
      part[(s * 4 + q) * 128 + b] = p0;
    }
    __syncthreads();
    if (tid < 256) {
      int ss = tid >> 7, bb = tid & 127;
      yl[ss * 128 + bb] = part[(ss * 4) * 128 + bb] + part[(ss * 4 + 1) * 128 + bb] +
                          part[(ss * 4 + 2) * 128 + bb] + part[(ss * 4 + 3) * 128 + bb];
    }
    __syncthreads();
    {
      double y1a = yl[128 + 2 * lane], y1b = yl[128 + 2 * lane + 1];
      double vp = 0.0;
      #pragma unroll
      for (int t = 0; t < 8; ++t)
        vp += yl[128 + 16 * t + wv] * (rv[2 * t] * y1a + rv[2 * t + 1] * y1b);
      #pragma unroll
      for (int off = 1; off < 64; off <<= 1) vp += __shfl_xor(vp, off, 64);
      if (lane == 0) part[wv] = vp;
    }
    __syncthreads();
    if (tid == 0) {
      double v = 0.0;
      #pragma unroll
      for (int k = 0; k < 16; ++k) v += part[k];
      double zn = (site == 0) ? *Zp : 1.0;
      double ps0 = v / zn;
      double u = (double)randu[site];
      bool take0 = u < ps0;
      double pp = take0 ? ps0 : (1.0 - ps0);
      ctrl[0] = take0 ? 1.0 : 0.0;
      ctrl[1] = 1.0 / sqrt(pp * zn);
      out[2 * site] = take0 ? 0.0f : 1.0f;
      out[2 * site + 1] = take0 ? 1.0f : 0.0f;
    }
    __syncthreads();
    {
      int k = (ctrl[0] != 0.0) ? 1 : 0;
      double sc = ctrl[1];
      if (tid < 128)
        ast(&wbuf[(size_t)(site + 1) * 128 + tid], yl[k * 128 + tid] * sc);
    }
    __syncthreads();
  }
}

// ---------------------------------------------------------------- diagnostics
__global__ void k_diag(float* __restrict__ out, int n, float mb) {
  int i = blockIdx.x * blockDim.x + threadIdx.x;
  if (i < n) out[i] = (i == 0) ? mb : ((i & 1) ? 0.75f : 0.25f);
}

// ---------------------------------------------------------------- plans
template <typename TT, typename TR>
struct Plan {
  size_t oTk, oR, oRs0, oW, oZ, need;
  Plan() {
    oTk = 0;
    oR = oTk + sizeof(TT) * (size_t)NS * 32768;
    oRs0 = oR + sizeof(TR) * (size_t)NS * 16384;
    oW = oRs0 + sizeof(TR) * 16384;
    oZ = oW + 8ull * (NS + 1) * 128;
    need = oZ + 64;
  }
};

template <typename TT>
struct PlanN {
  size_t oTk, oScr, oR, oRs0, oW, oZ, need;
  int splitP;
  PlanN() {
    splitP = (sizeof(TT) == 8) ? 256 : 128;
    oTk = 0;
    size_t tkB = sizeof(TT) * (size_t)NS * 32768;
    oScr = tkB;
    size_t yB = 8ull * NS * 16384;
    size_t bhiB = 8ull * (size_t)(512 - splitP) * 4 * 16384;
    size_t scrB = (yB > bhiB) ? yB : bhiB;
    oR = oScr + scrB;
    oRs0 = oR + 8ull * 512 * 16384;
    oW = oRs0 + 8ull * 16384;
    oZ = oW + 8ull * 513 * 128;
    need = oZ + 64;
  }
};

template <typename TT, typename TR>
static void run_cfg(const float* params, const float* randu, float* out,
                    char* ws, hipStream_t stream) {
  Plan<TT, TR> P;
  TT* Tk = (TT*)(ws + P.oTk);
  TR* Rbuf = (TR*)(ws + P.oR);
  TR* Yscr = Rbuf;
  TR* Rs0 = (TR*)(ws + P.oRs0);
  double* wbuf = (double*)(ws + P.oW);
  double* Zp = (double*)(ws + P.oZ);
  k_cayley<TT, TR><<<dim3(NS), dim3(256), 0, stream>>>(params, Tk, Yscr);
  k_w2<TT, TR><<<dim3(NS), dim3(256), 0, stream>>>(params, Yscr, Tk);
  k_init<TR><<<dim3(4096), dim3(256), 0, stream>>>(wbuf, Rbuf);
  k_scan<TT, TR><<<dim3(256), dim3(512), 0, stream>>>(Tk, Rbuf, Rs0, Zp);
  k_sample<TT, TR><<<dim3(16), dim3(1024), 0, stream>>>(Tk, Rbuf, wbuf, Zp, randu, out);
}

template <typename TT>
static void run_pairN(const float* params, const float* randu, float* out,
                      char* ws, hipStream_t stream) {
  PlanN<TT> P;
  TT* Tk = (TT*)(ws + P.oTk);
  double* Yscr = (double*)(ws + P.oScr);
  double* Bhi = (double*)(ws + P.oScr);
  double* Blo = (double*)(ws + P.oTk + sizeof(TT) * (size_t)512 * 32768);
  double* Rodd = (double*)(ws + P.oR);
  double* Rs0 = (double*)(ws + P.oRs0);
  double* wbuf = (double*)(ws + P.oW);
  double* Zp = (double*)(ws + P.oZ);
  const int sp = P.splitP;
  k_cayley<TT, double><<<dim3(NS), dim3(256), 0, stream>>>(params, Tk, Yscr);
  k_w2<TT, double><<<dim3(NS), dim3(256), 0, stream>>>(params, Yscr, Tk);
  k_init2<<<dim3(2048), dim3(256), 0, stream>>>(wbuf, Rodd);
  k_pair2<TT><<<dim3((512 - sp) * 4), dim3(256), 0, stream>>>(Tk, Bhi, sp);
  k_pair2<TT><<<dim3(sp * 4), dim3(256), 0, stream>>>(Tk, Blo, 0);
  k_scan3<<<dim3(256), dim3(512), 0, stream>>>(Blo, Bhi, sp, Rodd, Rs0, Zp);
  k_sample4<<<dim3(32), dim3(512), 0, stream>>>(Blo, Bhi, sp, Rodd, wbuf, Zp,
                                                randu, out);
}

extern "C" void kernel_launch(void* const* d_in, const int* in_sizes, int n_in,
                              void* d_out, int out_size, void* d_ws, size_t ws_size,
                              hipStream_t stream) {
  const float* params = (const float*)d_in[0];
  const float* randu = (const float*)d_in[1];
  float* out = (float*)d_out;
  char* ws = (char*)d_ws;
  if (ws_size >= PlanN<double>().need) {
    run_pairN<double>(params, randu, out, ws, stream);
  } else if (ws_size >= PlanN<float>().need) {
    run_pairN<float>(params, randu, out, ws, stream);
  } else if (ws_size >= Plan<double, double>().need) {
    run_cfg<double, double>(params, randu, out, ws, stream);
  } else if (ws_size >= Plan<float, double>().need) {
    run_cfg<float, double>(params, randu, out, ws, stream);
  } else if (ws_size >= Plan<float, float>().need) {
    run_cfg<float, float>(params, randu, out, ws, stream);
  } else {
    k_diag<<<dim3((out_size + 255) / 256), dim3(256), 0, stream>>>(
        out, out_size, (float)(ws_size >> 20));
  }
}